// Round 2
// baseline (199.009 us; speedup 1.0000x reference)
//
#include <hip/hip_runtime.h>
#include <stdint.h>
#include <stddef.h>

// ClusterLayer: q = normalize_rows( 1 / (1 + ||z-c||^2) )
// N=200000 rows, D=256, KC=256 clusters. fp32 in/out; cross-term via bf16 MFMA.
// R1: no LDS, no barriers. One 16-row tile per wave; B fragments read from L2
// in a prep-reordered fragment-contiguous layout (1KB contiguous per wave-load).

#define D 256
#define KC 256

typedef __attribute__((ext_vector_type(8))) short short8;  // 8 bf16 (4 VGPRs)
typedef __attribute__((ext_vector_type(4))) float f32x4;   // MFMA accumulator

// fp32 -> bf16, round-to-nearest-even (branch-free)
__device__ __forceinline__ short f2bf(float f) {
    uint32_t u = __builtin_bit_cast(uint32_t, f);
    u += 0x7FFFu + ((u >> 16) & 1u);
    return (short)(u >> 16);
}

// csq[k] = ||c_k||^2 ; one wave per cluster row.
__global__ void prep_csq(const float* __restrict__ C, float* __restrict__ csq) {
    const int k = blockIdx.x;
    const int l = threadIdx.x;  // 0..63
    float4 v = *(const float4*)(C + k * D + l * 4);
    float s = v.x * v.x + v.y * v.y + v.z * v.z + v.w * v.w;
#pragma unroll
    for (int off = 32; off > 0; off >>= 1) s += __shfl_down(s, off);
    if (l == 0) csq[k] = s;
}

// Reorder C into MFMA-B fragment order, bf16:
// Bf[((kk*16 + ct)*64 + lane)*8 + e] = bf16( C[(ct*16 + (lane&15))*D + kk*32 + (lane>>4)*8 + e] )
// so each wave's B-frag load for (kk,ct) is 64 lanes x 16B fully contiguous.
__global__ void prep_reorder(const float* __restrict__ C, unsigned short* __restrict__ Bf) {
    const int kk = blockIdx.x >> 4;   // 0..7
    const int ct = blockIdx.x & 15;   // 0..15
    const int lane = threadIdx.x;     // 0..63
    const int l15 = lane & 15;
    const int lg = lane >> 4;
    const float* src = C + (size_t)(ct * 16 + l15) * D + kk * 32 + lg * 8;
    float4 a0 = *(const float4*)(src);
    float4 a1 = *(const float4*)(src + 4);
    ushort4 p0, p1;
    p0.x = (unsigned short)f2bf(a0.x); p0.y = (unsigned short)f2bf(a0.y);
    p0.z = (unsigned short)f2bf(a0.z); p0.w = (unsigned short)f2bf(a0.w);
    p1.x = (unsigned short)f2bf(a1.x); p1.y = (unsigned short)f2bf(a1.y);
    p1.z = (unsigned short)f2bf(a1.z); p1.w = (unsigned short)f2bf(a1.w);
    unsigned short* dst = Bf + ((size_t)(kk * 16 + ct) * 64 + lane) * 8;
    *(ushort4*)(dst) = p0;
    *(ushort4*)(dst + 4) = p1;
}

// 4 waves/block, no LDS, no barriers. Each wave: one 16-row tile, all 256 cols.
__global__ void __launch_bounds__(256, 4)
main_kernel(const float* __restrict__ z,
            const unsigned short* __restrict__ Bf,
            const float* __restrict__ csq,
            float* __restrict__ out, int nrows) {
    const int tid  = threadIdx.x;
    const int lane = tid & 63;
    const int wave = tid >> 6;
    const int l15  = lane & 15;
    const int lg   = lane >> 4;          // 0..3

    const int gwid = blockIdx.x * 4 + wave;
    const int row0 = gwid * 16;
    if (row0 >= nrows) return;           // N divides evenly; guard anyway

    // A source: lane reads z[row0 + l15][kk*32 + lg*8 .. +8]
    const float* zrow = z + (size_t)(row0 + l15) * D + lg * 8;
    // B source: per-lane fragment base
    const unsigned short* blane = Bf + (size_t)lane * 8;

    f32x4 acc[16];
    const f32x4 zero4 = {0.f, 0.f, 0.f, 0.f};
#pragma unroll
    for (int ct = 0; ct < 16; ++ct) acc[ct] = zero4;
    float zsq_part = 0.f;

    // prefetch kk=0 A
    float4 a0 = *(const float4*)(zrow);
    float4 a1 = *(const float4*)(zrow + 4);

#pragma unroll
    for (int kk = 0; kk < 8; ++kk) {
        float4 n0, n1;
        if (kk < 7) {  // prefetch next A while MFMAs run
            n0 = *(const float4*)(zrow + (kk + 1) * 32);
            n1 = *(const float4*)(zrow + (kk + 1) * 32 + 4);
        }
        zsq_part += a0.x * a0.x + a0.y * a0.y + a0.z * a0.z + a0.w * a0.w +
                    a1.x * a1.x + a1.y * a1.y + a1.z * a1.z + a1.w * a1.w;
        short8 af;
        af[0] = f2bf(a0.x); af[1] = f2bf(a0.y); af[2] = f2bf(a0.z); af[3] = f2bf(a0.w);
        af[4] = f2bf(a1.x); af[5] = f2bf(a1.y); af[6] = f2bf(a1.z); af[7] = f2bf(a1.w);
        const unsigned short* bp = blane + (size_t)kk * 16 * 512;  // 512 shorts per (kk,ct) frag-block
#pragma unroll
        for (int ct = 0; ct < 16; ++ct) {
            short8 bf = *(const short8*)(bp + (size_t)ct * 512);
            acc[ct] = __builtin_amdgcn_mfma_f32_16x16x32_bf16(af, bf, acc[ct], 0, 0, 0);
        }
        a0 = n0; a1 = n1;
    }

    // ||z_row||^2: lane holds partial for row l15; sum over the 4 lane-groups
    float zsq = zsq_part;
    zsq += __shfl_xor(zsq, 16);
    zsq += __shfl_xor(zsq, 32);
    // redistribute to C/D layout rows: row = lg*4 + j
    float zsqj[4];
#pragma unroll
    for (int j = 0; j < 4; ++j) zsqj[j] = __shfl(zsq, lg * 4 + j);

    // c_sq for this lane's 16 columns (col = ct*16 + l15) — loaded post-MFMA (L2-hot)
    float csqr[16];
#pragma unroll
    for (int ct = 0; ct < 16; ++ct) csqr[ct] = csq[ct * 16 + l15];

    // q = 1/(1+dist); accumulate per-lane partial row sums
    float rs[4] = {0.f, 0.f, 0.f, 0.f};
#pragma unroll
    for (int ct = 0; ct < 16; ++ct) {
#pragma unroll
        for (int j = 0; j < 4; ++j) {
            float dist = zsqj[j] + csqr[ct] - 2.0f * acc[ct][j];
            dist = fmaxf(dist, 0.f);
            float qv = 1.0f / (1.0f + dist);
            acc[ct][j] = qv;
            rs[j] += qv;
        }
    }
    // reduce row sums across the 16-lane column group
#pragma unroll
    for (int j = 0; j < 4; ++j) {
        float s = rs[j];
        s += __shfl_xor(s, 1);
        s += __shfl_xor(s, 2);
        s += __shfl_xor(s, 4);
        s += __shfl_xor(s, 8);
        rs[j] = 1.0f / s;
    }
    // store: lane writes col ct*16+l15 of rows row0 + lg*4 + j
#pragma unroll
    for (int j = 0; j < 4; ++j) {
        float* orow = out + (size_t)(row0 + lg * 4 + j) * KC + l15;
#pragma unroll
        for (int ct = 0; ct < 16; ++ct) orow[ct * 16] = acc[ct][j] * rs[j];
    }
}

extern "C" void kernel_launch(void* const* d_in, const int* in_sizes, int n_in,
                              void* d_out, int out_size, void* d_ws, size_t ws_size,
                              hipStream_t stream) {
    const float* zp = (const float*)d_in[0];
    const float* Cp = (const float*)d_in[1];
    const int N = in_sizes[0] / D;  // 200000
    unsigned short* Bf = (unsigned short*)d_ws;                          // 128KB bf16 frag-ordered
    float* csq = (float*)((char*)d_ws + (size_t)KC * D * sizeof(unsigned short));  // 1KB

    prep_csq<<<KC, 64, 0, stream>>>(Cp, csq);
    prep_reorder<<<128, 64, 0, stream>>>(Cp, Bf);

    const int tiles = (N + 15) / 16;           // 12500
    const int nblk = (tiles + 3) / 4;          // 3125 blocks x 4 waves
    main_kernel<<<nblk, 256, 0, stream>>>(zp, Bf, csq, (float*)d_out, N);
}